// Round 2
// baseline (254.783 us; speedup 1.0000x reference)
//
#include <hip/hip_runtime.h>
#include <hip/hip_fp16.h>

#define BB 4
#define CC 3
#define HH 384
#define WW 384
#define FF 5
#define KK 25            // FF*FF
#define HW (HH*WW)

#define TX 64            // tile width (pixels) — 32 threads x 2 px
#define TY 8             // tile height
#define MARG 8           // offset safety margin (|N(0,1)| max ~5.5 + tap ±2)
#define RH (TY + 2*MARG + 1)   // 25 staged rows  [Y-8 .. Y+16]
#define RW (TX + 2*MARG)       // 80 staged cols  [X-8 .. X+71]
#define SMN (RH*RW)            // 2000 pixels * 8B = 16000 B LDS

typedef float fx2 __attribute__((ext_vector_type(2)));

__device__ __forceinline__ fx2 nt_load2(const float* p) {
    return __builtin_nontemporal_load((const fx2*)p);
}

// pack one pixel (3 fp32 channels) -> 8B: x = h(c0)|h(c1)<<16, y = h(c2)
__device__ __forceinline__ uint2 pack_px(float c0, float c1, float c2) {
    __half2 h01 = __floats2half2_rn(c0, c1);
    uint2 r;
    r.x = *(const unsigned int*)&h01;
    r.y = (unsigned int)__half_as_ushort(__float2half_rn(c2));
    return r;
}

__device__ __forceinline__ void unpack_px(uint2 r, float& c0, float& c1, float& c2) {
    float2 f01 = __half22float2(*(const __half2*)&r.x);
    c0 = f01.x; c1 = f01.y;
    c2 = __half2float(*(const __half*)&r.y);
}

// One fused kernel: stage 25x80 fp16 pixel tile in LDS, then 2 px/thread
// deformable-sepconv with all bilinear taps served from LDS (ds_read_b64).
// Rare out-of-region offsets (|off|>~6) fall back to global fp32 reads.
__global__ __launch_bounds__(256) void dsepconv_kernel(
    const float* __restrict__ inp,
    const float* __restrict__ vert,
    const float* __restrict__ horiz,
    const float* __restrict__ offx,
    const float* __restrict__ offy,
    const float* __restrict__ mask,
    float* __restrict__ out)
{
    __shared__ uint2 smem[SMN];

    int tx = threadIdx.x & 31;
    int ty = threadIdx.x >> 5;
    int X  = blockIdx.x * TX;
    int Y  = blockIdx.y * TY;
    int xb = X + tx * 2;                 // even
    int y  = Y + ty;
    int b  = blockIdx.z;
    int ylo = Y - MARG, xlo = X - MARG;
    int planeoff = y * WW + xb;          // 8B aligned

    const float* c0p = inp + ((size_t)b * CC + 0) * HW;
    const float* c1p = inp + ((size_t)b * CC + 1) * HW;
    const float* c2p = inp + ((size_t)b * CC + 2) * HW;

    // ---- stage the input region (coalesced row segments, fp32 -> fp16) ----
    for (int p = threadIdx.x; p < SMN; p += 256) {
        int r = p / RW;                  // constant div -> magic mul
        int c = p - r * RW;
        int gy = min(max(ylo + r, 0), HH - 1);
        int gx = min(max(xlo + c, 0), WW - 1);
        int o  = gy * WW + gx;
        smem[p] = pack_px(c0p[o], c1p[o], c2p[o]);
    }
    __syncthreads();

    fx2 v2[FF], h2[FF];
#pragma unroll
    for (int f = 0; f < FF; ++f) {
        v2[f] = nt_load2(vert  + (b * FF + f) * HW + planeoff);
        h2[f] = nt_load2(horiz + (b * FF + f) * HW + planeoff);
    }

    float acc[2][3] = {{0.f,0.f,0.f},{0.f,0.f,0.f}};
    const float fy = (float)y;

    for (int ki = 0; ki < FF; ++ki) {
        float dy = fy + (float)(ki - 2);
        const float* ox_p = offx + (size_t)(b * KK + ki * FF) * HW + planeoff;
        const float* oy_p = offy + (size_t)(b * KK + ki * FF) * HW + planeoff;
        const float* m_p  = mask + (size_t)(b * KK + ki * FF) * HW + planeoff;
#pragma unroll
        for (int kj = 0; kj < FF; ++kj) {
            fx2 ox2 = nt_load2(ox_p + kj * HW);
            fx2 oy2 = nt_load2(oy_p + kj * HW);
            fx2 m2  = nt_load2(m_p  + kj * HW);
#pragma unroll
            for (int p = 0; p < 2; ++p) {
                float wt = v2[ki][p] * h2[kj][p] * m2[p];
                float py = oy2[p] + dy;
                float px = ox2[p] + (float)(xb + p + kj - 2);
                py = fminf(fmaxf(py, 0.f), (float)(HH - 1));
                px = fminf(fmaxf(px, 0.f), (float)(WW - 1));
                float y0f = floorf(py);
                float x0f = floorf(px);
                float wy = py - y0f;
                float wx = px - x0f;
                int y0 = (int)y0f;
                int x0 = (int)x0f;

                int y0r = y0 - ylo;
                int x0r = x0 - xlo;
                bool ok = ((unsigned)y0r <= (unsigned)(RH - 2)) &
                          ((unsigned)x0r <= (unsigned)(RW - 2));

                float s00c0,s00c1,s00c2, s01c0,s01c1,s01c2;
                float s10c0,s10c1,s10c2, s11c0,s11c1,s11c2;
                if (ok) {
                    int dxo = (x0 < WW - 1) ? 1 : 0;
                    int dyo = (y0 < HH - 1) ? RW : 0;
                    int a   = y0r * RW + x0r;
                    uint2 r00 = smem[a];
                    uint2 r01 = smem[a + dxo];
                    uint2 r10 = smem[a + dyo];
                    uint2 r11 = smem[a + dyo + dxo];
                    unpack_px(r00, s00c0, s00c1, s00c2);
                    unpack_px(r01, s01c0, s01c1, s01c2);
                    unpack_px(r10, s10c0, s10c1, s10c2);
                    unpack_px(r11, s11c0, s11c1, s11c2);
                } else {            // statistically never taken; correctness net
                    int x1 = min(x0 + 1, WW - 1);
                    int y1 = min(y0 + 1, HH - 1);
                    int o00 = y0 * WW + x0, o01 = y0 * WW + x1;
                    int o10 = y1 * WW + x0, o11 = y1 * WW + x1;
                    s00c0 = c0p[o00]; s00c1 = c1p[o00]; s00c2 = c2p[o00];
                    s01c0 = c0p[o01]; s01c1 = c1p[o01]; s01c2 = c2p[o01];
                    s10c0 = c0p[o10]; s10c1 = c1p[o10]; s10c2 = c2p[o10];
                    s11c0 = c0p[o11]; s11c1 = c1p[o11]; s11c2 = c2p[o11];
                }

                float w00 = (1.f - wy) * (1.f - wx);
                float w01 = (1.f - wy) * wx;
                float w10 = wy * (1.f - wx);
                float w11 = wy * wx;

                acc[p][0] += wt * (s00c0*w00 + s01c0*w01 + s10c0*w10 + s11c0*w11);
                acc[p][1] += wt * (s00c1*w00 + s01c1*w01 + s10c1*w10 + s11c1*w11);
                acc[p][2] += wt * (s00c2*w00 + s01c2*w01 + s10c2*w10 + s11c2*w11);
            }
        }
    }

#pragma unroll
    for (int c = 0; c < CC; ++c) {
        fx2 o; o.x = acc[0][c]; o.y = acc[1][c];
        *(fx2*)(out + ((size_t)b * CC + c) * HW + planeoff) = o;
    }
}

extern "C" void kernel_launch(void* const* d_in, const int* in_sizes, int n_in,
                              void* d_out, int out_size, void* d_ws, size_t ws_size,
                              hipStream_t stream) {
    const float* inp   = (const float*)d_in[0];
    const float* vert  = (const float*)d_in[1];
    const float* horiz = (const float*)d_in[2];
    const float* offx  = (const float*)d_in[3];
    const float* offy  = (const float*)d_in[4];
    const float* mask  = (const float*)d_in[5];
    float* out = (float*)d_out;

    dim3 grid(WW / TX, HH / TY, BB);   // 6 x 48 x 4
    dsepconv_kernel<<<grid, 256, 0, stream>>>(
        inp, vert, horiz, offx, offy, mask, out);
}